// Round 6
// baseline (459.700 us; speedup 1.0000x reference)
//
#include <hip/hip_runtime.h>
#include <hip/hip_bf16.h>

#define SQ 4096
#define HID 1024
#define INTER_DIM 4096
#define NH 16
#define DH 64
#define SCALE_Q 0.18033688f  // 0.125 * log2(e), folded into q_w/q_b

typedef __attribute__((ext_vector_type(4))) float f32x4;
typedef __attribute__((ext_vector_type(16))) float f32x16;
typedef __attribute__((ext_vector_type(8))) short bf16x8;

__device__ __forceinline__ float bf2f(unsigned short u) {
  union { float f; unsigned int i; } v; v.i = ((unsigned int)u) << 16; return v.f;
}
__device__ __forceinline__ unsigned short f2bf(float f) {
  union { float f; unsigned int i; } v; v.f = f;
  unsigned int i = v.i;
  return (unsigned short)((i + 0x7FFFu + ((i >> 16) & 1u)) >> 16);
}

__device__ __forceinline__ void load_lds16(const void* g, void* l) {
  __builtin_amdgcn_global_load_lds(
      (const __attribute__((address_space(1))) void*)g,
      (__attribute__((address_space(3))) void*)l, 16, 0, 0);
}

__device__ __forceinline__ int cvtpk_bf16(float a, float b) {
  int r;
  asm("v_cvt_pk_bf16_f32 %0, %1, %2" : "=v"(r) : "v"(a), "v"(b));
  return r;
}

// native 2^x (log2-domain softmax). s_nop covers trans->VALU hazard.
__device__ __forceinline__ float fexp2(float x) {
  float r;
  asm("v_exp_f32 %0, %1\n\ts_nop 1" : "=v"(r) : "v"(x));
  return r;
}

// ---------------- fused weight conversion fp32 -> bf16 ----------------
__global__ __launch_bounds__(256) void cvt6_kernel(
    const float* __restrict__ s0, const float* __restrict__ s1,
    const float* __restrict__ s2, const float* __restrict__ s3,
    const float* __restrict__ s4, const float* __restrict__ s5,
    unsigned short* __restrict__ dst) {
  const int b = blockIdx.x;
  const float* src;
  int lb;
  size_t base4;
  if (b < 4096) {
    const int r = b >> 10;
    lb = b & 1023;
    src = (r == 0) ? s0 : (r == 1) ? s1 : (r == 2) ? s2 : s3;
    base4 = (size_t)r << 18;
  } else if (b < 8192) {
    lb = b - 4096; src = s4; base4 = 1u << 20;
  } else {
    lb = b - 8192; src = s5; base4 = 2u << 20;
  }
  const float sc = (b < 1024) ? SCALE_Q : 1.0f;
  const int i = lb * 256 + threadIdx.x;
  const float4 v4 = ((const float4*)src)[i];
  ushort4 o4;
  o4.x = f2bf(v4.x * sc); o4.y = f2bf(v4.y * sc);
  o4.z = f2bf(v4.z * sc); o4.w = f2bf(v4.w * sc);
  ((ushort4*)dst)[base4 + i] = o4;
}

// ---------------- concat q/k/v biases (q scaled) ----------------
__global__ __launch_bounds__(256) void bias3_kernel(
    const float* __restrict__ qb, const float* __restrict__ kb,
    const float* __restrict__ vb, float* __restrict__ dst) {
  const int b = blockIdx.x, t = threadIdx.x;
  const float* s = (b == 0) ? qb : (b == 1) ? kb : vb;
  float4 v = ((const float4*)s)[t];
  if (b == 0) { v.x *= SCALE_Q; v.y *= SCALE_Q; v.z *= SCALE_Q; v.w *= SCALE_Q; }
  ((float4*)dst)[b * 256 + t] = v;
}

// ---------------- mean-only layernorm -> bf16 ----------------
__global__ __launch_bounds__(256) void ln_kernel(
    const float* __restrict__ x, const float* __restrict__ w,
    const float* __restrict__ b, unsigned short* __restrict__ out) {
  const int row = blockIdx.x;
  const int t = threadIdx.x;
  const float4 v = ((const float4*)(x + (size_t)row * HID))[t];
  float s = v.x + v.y + v.z + v.w;
  #pragma unroll
  for (int off = 32; off > 0; off >>= 1) s += __shfl_xor(s, off);
  __shared__ float red[4];
  if ((t & 63) == 0) red[t >> 6] = s;
  __syncthreads();
  const float mean = (red[0] + red[1] + red[2] + red[3]) * (1.0f / HID);
  const float4 wv = ((const float4*)w)[t];
  const float4 bv = ((const float4*)b)[t];
  ushort4 o;
  o.x = f2bf(wv.x * (v.x - mean) + bv.x);
  o.y = f2bf(wv.y * (v.y - mean) + bv.y);
  o.z = f2bf(wv.z * (v.z - mean) + bv.z);
  o.w = f2bf(wv.w * (v.w - mean) + bv.w);
  ((ushort4*)(out + (size_t)row * HID))[t] = o;
}

// ---------------- 256x256 GEMM, BK=32, 8 waves (2Mx4N), 32x32x16 MFMA ----
// 2-phase double-buffered LDS (64KB). C[M][N] = A[M][K]*B[N][K]^T + bias.
// MODE 1: bf16 relu(acc+bias)
// MODE 4: fused QKV: col<2048 -> bf16 C0[row*2048+col];
//         col>=2048 -> bf16 transposed C1[(col-2048)*M + row]
// MODE 6: split-K/4 via blockIdx.z: z==3 -> f32 C0 = acc+bias;
//         z<3 -> bf16 C1[z][row*N+col] = acc
template <int MODE>
__global__ __launch_bounds__(512, 1) void gemm256(
    const unsigned short* __restrict__ A, const unsigned short* __restrict__ B,
    const float* __restrict__ bias, void* __restrict__ C0,
    void* __restrict__ C1, int M, int N, int K) {
  __shared__ __align__(16) unsigned short As[2][8192];
  __shared__ __align__(16) unsigned short Bs[2][8192];
  const int t = threadIdx.x;
  const int lane = t & 63;
  const int w = t >> 6;
  const int ql = lane & 31, hi = lane >> 5;
  const int wm = w >> 2, wn = w & 3;
  const int bR = blockIdx.x * 256;
  const int bC = blockIdx.y * 256;
  const int Keff = (MODE == 6) ? (K >> 2) : K;
  const int kBase = (MODE == 6) ? blockIdx.z * Keff : 0;

  f32x16 acc[4][2];
  #pragma unroll
  for (int mf = 0; mf < 4; ++mf)
    #pragma unroll
    for (int nf = 0; nf < 2; ++nf) acc[mf][nf] = 0.f;

  // staging: 1024 chunks of 16B per matrix per K-tile; thread t handles
  // chunks t and t+512. chunk c -> row c>>2, swizzled slot (c&3)^(row&3).
  const int r0 = t >> 2, s0 = (t & 3) ^ (r0 & 3);
  const int r1 = r0 + 128, s1 = (t & 3) ^ (r1 & 3);
  const unsigned short* gA0 = A + (size_t)(bR + r0) * K + kBase + s0 * 8;
  const unsigned short* gA1 = A + (size_t)(bR + r1) * K + kBase + s1 * 8;
  const unsigned short* gB0 = B + (size_t)(bC + r0) * K + kBase + s0 * 8;
  const unsigned short* gB1 = B + (size_t)(bC + r1) * K + kBase + s1 * 8;

  load_lds16(gA0, &As[0][w * 512]);
  load_lds16(gA1, &As[0][4096 + w * 512]);
  load_lds16(gB0, &Bs[0][w * 512]);
  load_lds16(gB1, &Bs[0][4096 + w * 512]);
  __syncthreads();

  const int nk = Keff >> 5;
  for (int kt = 0; kt < nk; ++kt) {
    const int buf = kt & 1;
    if (kt + 1 < nk) {
      const int k0 = (kt + 1) << 5;
      load_lds16(gA0 + k0, &As[buf ^ 1][w * 512]);
      load_lds16(gA1 + k0, &As[buf ^ 1][4096 + w * 512]);
      load_lds16(gB0 + k0, &Bs[buf ^ 1][w * 512]);
      load_lds16(gB1 + k0, &Bs[buf ^ 1][4096 + w * 512]);
    }
    bf16x8 af[2][4], bfr[2][2];
    #pragma unroll
    for (int ks = 0; ks < 2; ++ks) {
      #pragma unroll
      for (int mf = 0; mf < 4; ++mf) {
        const int row = wm * 128 + mf * 32 + ql;
        af[ks][mf] = *(const bf16x8*)
            &As[buf][row * 32 + ((ks * 16 + hi * 8) ^ ((row & 3) << 3))];
      }
      #pragma unroll
      for (int nf = 0; nf < 2; ++nf) {
        const int col = wn * 64 + nf * 32 + ql;
        bfr[ks][nf] = *(const bf16x8*)
            &Bs[buf][col * 32 + ((ks * 16 + hi * 8) ^ ((col & 3) << 3))];
      }
    }
    __builtin_amdgcn_s_setprio(1);
    #pragma unroll
    for (int ks = 0; ks < 2; ++ks)
      #pragma unroll
      for (int mf = 0; mf < 4; ++mf)
        #pragma unroll
        for (int nf = 0; nf < 2; ++nf)
          acc[mf][nf] = __builtin_amdgcn_mfma_f32_32x32x16_bf16(
              af[ks][mf], bfr[ks][nf], acc[mf][nf], 0, 0, 0);
    __builtin_amdgcn_s_setprio(0);
    __syncthreads();
  }

  // epilogue: C row = reg-decode (A side), col = ql (B side)
  #pragma unroll
  for (int mf = 0; mf < 4; ++mf) {
    #pragma unroll
    for (int nf = 0; nf < 2; ++nf) {
      const int col = bC + wn * 64 + nf * 32 + ql;
      const float bv = bias[col];
      const int rowb = bR + wm * 128 + mf * 32;
      if (MODE == 4) {
        if (col < 2048) {
          #pragma unroll
          for (int r = 0; r < 16; ++r) {
            const int row = rowb + (r & 3) + 8 * (r >> 2) + 4 * hi;
            ((unsigned short*)C0)[(size_t)row * 2048 + col] =
                f2bf(acc[mf][nf][r] + bv);
          }
        } else {
          #pragma unroll
          for (int r2 = 0; r2 < 4; ++r2) {
            const int row = rowb + 8 * r2 + 4 * hi;
            ushort4 o4;
            o4.x = f2bf(acc[mf][nf][4 * r2 + 0] + bv);
            o4.y = f2bf(acc[mf][nf][4 * r2 + 1] + bv);
            o4.z = f2bf(acc[mf][nf][4 * r2 + 2] + bv);
            o4.w = f2bf(acc[mf][nf][4 * r2 + 3] + bv);
            *(ushort4*)&((unsigned short*)C1)[(size_t)(col - 2048) * M + row] = o4;
          }
        }
      } else if (MODE == 1) {
        #pragma unroll
        for (int r = 0; r < 16; ++r) {
          const int row = rowb + (r & 3) + 8 * (r >> 2) + 4 * hi;
          ((unsigned short*)C0)[(size_t)row * N + col] =
              f2bf(fmaxf(acc[mf][nf][r] + bv, 0.f));
        }
      } else {  // MODE 6
        if (blockIdx.z == 3) {
          #pragma unroll
          for (int r = 0; r < 16; ++r) {
            const int row = rowb + (r & 3) + 8 * (r >> 2) + 4 * hi;
            ((float*)C0)[(size_t)row * N + col] = acc[mf][nf][r] + bv;
          }
        } else {
          unsigned short* P =
              (unsigned short*)C1 + (size_t)blockIdx.z * M * (size_t)N;
          #pragma unroll
          for (int r = 0; r < 16; ++r) {
            const int row = rowb + (r & 3) + 8 * (r >> 2) + 4 * hi;
            P[(size_t)row * N + col] = f2bf(acc[mf][nf][r]);
          }
        }
      }
    }
  }
}

// ---------------- 128x128 GEMM (proven), f32 out = acc+bias+res -----------
__global__ __launch_bounds__(256) void gemm128_res(
    const unsigned short* __restrict__ A, const unsigned short* __restrict__ B,
    const float* __restrict__ bias, const float* __restrict__ res,
    float* __restrict__ Cout, int M, int N, int K) {
  __shared__ __align__(16) unsigned short As[2][128 * 32];
  __shared__ __align__(16) unsigned short Bs[2][128 * 32];
  const int t = threadIdx.x;
  const int lane = t & 63;
  const int wave = t >> 6;
  const int g = lane >> 4;
  const int lr = lane & 15;
  const int waveM = wave >> 1, waveN = wave & 1;
  const int rowBase = blockIdx.x * 128;
  const int colBase = blockIdx.y * 128;

  f32x4 acc[4][4];
  #pragma unroll
  for (int m = 0; m < 4; ++m)
    #pragma unroll
    for (int n = 0; n < 4; ++n) acc[m][n] = (f32x4){0.f, 0.f, 0.f, 0.f};

  const int c0 = t, c1 = t + 256;
  const int r0s = c0 >> 2, s0 = (c0 & 3) ^ (r0s & 3);
  const int r1s = c1 >> 2, s1 = (c1 & 3) ^ (r1s & 3);
  const unsigned short* gA0 = A + (size_t)(rowBase + r0s) * K + s0 * 8;
  const unsigned short* gA1 = A + (size_t)(rowBase + r1s) * K + s1 * 8;
  const unsigned short* gB0 = B + (size_t)(colBase + r0s) * K + s0 * 8;
  const unsigned short* gB1 = B + (size_t)(colBase + r1s) * K + s1 * 8;

  load_lds16(gA0, &As[0][wave * 512]);
  load_lds16(gA1, &As[0][2048 + wave * 512]);
  load_lds16(gB0, &Bs[0][wave * 512]);
  load_lds16(gB1, &Bs[0][2048 + wave * 512]);
  __syncthreads();

  const int nk = K >> 5;
  for (int kt = 0; kt < nk; ++kt) {
    const int buf = kt & 1;
    if (kt + 1 < nk) {
      const int k0 = (kt + 1) << 5;
      load_lds16(gA0 + k0, &As[buf ^ 1][wave * 512]);
      load_lds16(gA1 + k0, &As[buf ^ 1][2048 + wave * 512]);
      load_lds16(gB0 + k0, &Bs[buf ^ 1][wave * 512]);
      load_lds16(gB1 + k0, &Bs[buf ^ 1][2048 + wave * 512]);
    }
    bf16x8 af[4], bfr[4];
    #pragma unroll
    for (int m = 0; m < 4; ++m) {
      const int r = waveM * 64 + m * 16 + lr;
      af[m] = *(const bf16x8*)&As[buf][r * 32 + ((g ^ (r & 3)) << 3)];
    }
    #pragma unroll
    for (int n = 0; n < 4; ++n) {
      const int c = waveN * 64 + n * 16 + lr;
      bfr[n] = *(const bf16x8*)&Bs[buf][c * 32 + ((g ^ (c & 3)) << 3)];
    }
    #pragma unroll
    for (int m = 0; m < 4; ++m)
      #pragma unroll
      for (int n = 0; n < 4; ++n)
        acc[m][n] = __builtin_amdgcn_mfma_f32_16x16x32_bf16(af[m], bfr[n],
                                                            acc[m][n], 0, 0, 0);
    __syncthreads();
  }

  const int crow0 = rowBase + waveM * 64;
  const int ccol0 = colBase + waveN * 64;
  #pragma unroll
  for (int n = 0; n < 4; ++n) {
    const int col = ccol0 + n * 16 + lr;
    const float bv = bias[col];
    #pragma unroll
    for (int m = 0; m < 4; ++m) {
      #pragma unroll
      for (int j = 0; j < 4; ++j) {
        const int row = crow0 + m * 16 + g * 4 + j;
        Cout[(size_t)row * N + col] =
            acc[m][n][j] + bv + res[(size_t)row * N + col];
      }
    }
  }
}

// ---------------- flash attention, swapped-QK, KV-split x2 ----------------
// grid 1024 blocks: s = by*32+bx; kvh = s&1; (head, qtile) from s>>1.
// 256 threads = 4 waves x 32 q-rows; KVBLK=64; 32 KV tiles per block.
// Writes UNNORMALIZED bf16 partials + (m,l) per q-row per head.
__global__ __launch_bounds__(256, 4) void attn_kernel(
    const unsigned short* __restrict__ QK,  // [SQ][2048]: Q 0-1023, K 1024-2047
    const unsigned short* __restrict__ Vt,  // [HID][SQ]
    unsigned short* __restrict__ ctxP,      // [2][SQ][HID] bf16 partials
    float2* __restrict__ ml) {              // [2][SQ][NH]
  const int s = blockIdx.y * gridDim.x + blockIdx.x;  // 0..1023
  const int kvh = s & 1;
  const int s2 = s >> 1;
  const int q6 = s2 >> 3;
  const int h = (s2 & 7) * 2 + (q6 >> 5);
  const int qt = q6 & 31;

  const int t = threadIdx.x;
  const int lane = t & 63;
  const int wave = t >> 6;
  const int ql = lane & 31;
  const int hi = lane >> 5;

  __shared__ __align__(16) unsigned short Ks[2][64 * 64];
  __shared__ __align__(16) unsigned short Vs[2][64 * 64];

  const int qbase = qt * 128 + wave * 32;
  const unsigned short* qptr =
      QK + (size_t)(qbase + ql) * 2048 + h * DH + hi * 8;
  bf16x8 qf[4];
  #pragma unroll
  for (int ks = 0; ks < 4; ++ks) qf[ks] = *(const bf16x8*)(qptr + ks * 16);

  const int cr = t >> 3, cs = t & 7;
  const int cr2 = cr + 32;
  const size_t kvoff = (size_t)kvh * 2048;
  const unsigned short* gK0 =
      QK + (kvoff + cr) * 2048 + 1024 + h * DH + ((cs ^ (cr & 7)) << 3);
  const unsigned short* gK1 =
      QK + (kvoff + cr2) * 2048 + 1024 + h * DH + ((cs ^ (cr2 & 7)) << 3);
  const unsigned short* gV0 =
      Vt + (size_t)(h * DH + cr) * SQ + kvoff + ((cs ^ (cr & 7)) << 3);
  const unsigned short* gV1 =
      Vt + (size_t)(h * DH + cr2) * SQ + kvoff + ((cs ^ (cr2 & 7)) << 3);

  float mreg = 0.f, lreg = 0.f;
  f32x16 oacc0 = 0.f, oacc1 = 0.f;

  load_lds16(gK0, &Ks[0][wave * 512]);
  load_lds16(gK1, &Ks[0][2048 + wave * 512]);
  load_lds16(gV0, &Vs[0][wave * 512]);
  load_lds16(gV1, &Vs[0][2048 + wave * 512]);

  const int NT = 32;  // half of SQ/64
  for (int kt = 0; kt < NT; ++kt) {
    const int buf = kt & 1;
    __syncthreads();
    if (kt + 1 < NT) {
      const size_t ko = (size_t)(kt + 1) * 64 * 2048;
      const int vo = (kt + 1) * 64;
      load_lds16(gK0 + ko, &Ks[buf ^ 1][wave * 512]);
      load_lds16(gK1 + ko, &Ks[buf ^ 1][2048 + wave * 512]);
      load_lds16(gV0 + vo, &Vs[buf ^ 1][wave * 512]);
      load_lds16(gV1 + vo, &Vs[buf ^ 1][2048 + wave * 512]);
    }
    const unsigned short* KsB = &Ks[buf][0];
    const unsigned short* VsB = &Vs[buf][0];

    f32x16 st0, st1;
    #pragma unroll
    for (int r = 0; r < 16; ++r) { st0[r] = -mreg; st1[r] = -mreg; }
    __builtin_amdgcn_s_setprio(1);
    #pragma unroll
    for (int ks = 0; ks < 4; ++ks) {
      const int sl = ((((ks << 1) | hi) ^ (ql & 7)) << 3);
      const bf16x8 k0 = *(const bf16x8*)&KsB[ql * 64 + sl];
      const bf16x8 k1 = *(const bf16x8*)&KsB[(32 + ql) * 64 + sl];
      st0 = __builtin_amdgcn_mfma_f32_32x32x16_bf16(k0, qf[ks], st0, 0, 0, 0);
      st1 = __builtin_amdgcn_mfma_f32_32x32x16_bf16(k1, qf[ks], st1, 0, 0, 0);
    }
    __builtin_amdgcn_s_setprio(0);

    bf16x8 vf0[4], vf1[4];
    #pragma unroll
    for (int ks = 0; ks < 4; ++ks) {
      const int sl = ((((ks << 1) | hi) ^ (ql & 7)) << 3);
      vf0[ks] = *(const bf16x8*)&VsB[ql * 64 + sl];
      vf1[ks] = *(const bf16x8*)&VsB[(32 + ql) * 64 + sl];
    }

    float tr[16];
    #pragma unroll
    for (int r = 0; r < 16; ++r) tr[r] = fmaxf(st0[r], st1[r]);
    #pragma unroll
    for (int s2_ = 8; s2_ > 0; s2_ >>= 1)
      #pragma unroll
      for (int r = 0; r < s2_; ++r) tr[r] = fmaxf(tr[r], tr[r + s2_]);
    const float mx = fmaxf(tr[0], __shfl_xor(tr[0], 32));

    if (!__all(mx <= 8.0f)) {  // defer-max rescale
      const float mpos = fmaxf(mx, 0.f);
      const float corr = fexp2(-mpos);
      mreg += mpos;
      lreg *= corr;
      #pragma unroll
      for (int r = 0; r < 16; ++r) { st0[r] -= mpos; st1[r] -= mpos; }
      #pragma unroll
      for (int r = 0; r < 16; ++r) {
        const float c = __shfl(corr, (r & 3) + 8 * (r >> 2) + 4 * hi);
        oacc0[r] *= c;
        oacc1[r] *= c;
      }
    }

    #pragma unroll
    for (int r = 0; r < 16; ++r) st0[r] = fexp2(st0[r]);
    #pragma unroll
    for (int r = 0; r < 16; ++r) st1[r] = fexp2(st1[r]);
    float ts[16];
    #pragma unroll
    for (int r = 0; r < 16; ++r) ts[r] = st0[r] + st1[r];
    #pragma unroll
    for (int s2_ = 8; s2_ > 0; s2_ >>= 1)
      #pragma unroll
      for (int r = 0; r < s2_; ++r) ts[r] += ts[r + s2_];
    lreg += ts[0] + __shfl_xor(ts[0], 32);

    union { int w[4]; bf16x8 v; } pa[4];
    #pragma unroll
    for (int half = 0; half < 2; ++half) {
      #pragma unroll
      for (int kk = 0; kk < 2; ++kk) {
        const int base = kk * 8;
        float p0, p1, p2, p3, p4, p5, p6, p7;
        if (half == 0) {
          p0 = st0[base + 0]; p1 = st0[base + 1]; p2 = st0[base + 2]; p3 = st0[base + 3];
          p4 = st0[base + 4]; p5 = st0[base + 5]; p6 = st0[base + 6]; p7 = st0[base + 7];
        } else {
          p0 = st1[base + 0]; p1 = st1[base + 1]; p2 = st1[base + 2]; p3 = st1[base + 3];
          p4 = st1[base + 4]; p5 = st1[base + 5]; p6 = st1[base + 6]; p7 = st1[base + 7];
        }
        const int d0 = cvtpk_bf16(p0, p1), sw0 = cvtpk_bf16(p4, p5);
        const int d1 = cvtpk_bf16(p2, p3), sw1 = cvtpk_bf16(p6, p7);
        auto a = __builtin_amdgcn_permlane32_swap(d0, sw0, false, false);
        auto b = __builtin_amdgcn_permlane32_swap(d1, sw1, false, false);
        const int ks = half * 2 + kk;
        pa[ks].w[0] = a[0]; pa[ks].w[1] = b[0];
        pa[ks].w[2] = a[1]; pa[ks].w[3] = b[1];
      }
    }

    __builtin_amdgcn_s_setprio(1);
    #pragma unroll
    for (int ks = 0; ks < 4; ++ks) {
      oacc0 = __builtin_amdgcn_mfma_f32_32x32x16_bf16(pa[ks].v, vf0[ks], oacc0, 0, 0, 0);
      oacc1 = __builtin_amdgcn_mfma_f32_32x32x16_bf16(pa[ks].v, vf1[ks], oacc1, 0, 0, 0);
    }
    __builtin_amdgcn_s_setprio(0);
  }

  // epilogue: unnormalized partials + (m,l)
  unsigned short* cpb = ctxP + (size_t)kvh * (SQ * (size_t)HID);
  #pragma unroll
  for (int r = 0; r < 16; ++r) {
    const int qq = (r & 3) + 8 * (r >> 2) + 4 * hi;
    unsigned short* cp = cpb + (size_t)(qbase + qq) * HID + h * DH + ql;
    cp[0] = f2bf(oacc0[r]);
    cp[32] = f2bf(oacc1[r]);
  }
  if (hi == 0) {
    float2 v; v.x = mreg; v.y = lreg;
    ml[(size_t)kvh * (SQ * NH) + (size_t)(qbase + ql) * NH + h] = v;
  }
}

// ---------------- attention combine: merge 2 KV-halves ----------------
__global__ __launch_bounds__(256) void combine2_kernel(
    const unsigned short* __restrict__ ctxP, const float2* __restrict__ ml,
    unsigned short* __restrict__ ctx) {
  const int i = blockIdx.x * 256 + threadIdx.x;  // 8-elem chunks
  const int row = i >> 7;
  const int dc = (i & 127) * 8;
  const int head = dc >> 6;
  const float2 a = ml[(size_t)row * NH + head];
  const float2 b = ml[(size_t)(SQ + row) * NH + head];
  const float M = fmaxf(a.x, b.x);
  const float w0 = fexp2(a.x - M), w1 = fexp2(b.x - M);
  const float inv = 1.0f / (w0 * a.y + w1 * b.y);
  const size_t off = (size_t)row * HID + dc;
  const size_t P = (size_t)SQ * HID;
  ushort4 p0a = *(const ushort4*)&ctxP[off];
  ushort4 p0b = *(const ushort4*)&ctxP[off + 4];
  ushort4 p1a = *(const ushort4*)&ctxP[P + off];
  ushort4 p1b = *(const ushort4*)&ctxP[P + off + 4];
  ushort4 oa, ob;
  oa.x = f2bf((w0 * bf2f(p0a.x) + w1 * bf2f(p1a.x)) * inv);
  oa.y = f2bf((w0 * bf2f(p0a.y) + w1 * bf2f(p1a.y)) * inv);
  oa.z = f2bf((w0 * bf2f(p0a.z) + w1 * bf2f(p1a.z)) * inv);
  oa.w = f2bf((w0 * bf2f(p0a.w) + w1 * bf2f(p1a.w)) * inv);
  ob.x = f2bf((w0 * bf2f(p0b.x) + w1 * bf2f(p1b.x)) * inv);
  ob.y = f2bf((w0 * bf2f(p0b.y) + w1 * bf2f(p1b.y)) * inv);
  ob.z = f2bf((w0 * bf2f(p0b.z) + w1 * bf2f(p1b.z)) * inv);
  ob.w = f2bf((w0 * bf2f(p0b.w) + w1 * bf2f(p1b.w)) * inv);
  *(ushort4*)&ctx[off] = oa;
  *(ushort4*)&ctx[off + 4] = ob;
}

// ---------------- FF2 combine: out += p0+p1+p2 + res ----------------
__global__ __launch_bounds__(256) void combine4_kernel(
    float* __restrict__ out, const unsigned short* __restrict__ parts,
    const float* __restrict__ res) {
  const int i = blockIdx.x * 256 + threadIdx.x;  // float4 index
  const size_t P = (size_t)SQ * HID;
  float4 o = ((const float4*)out)[i];
  const float4 r = ((const float4*)res)[i];
  const ushort4 a = ((const ushort4*)parts)[i];
  const ushort4 b = ((const ushort4*)(parts + P))[i];
  const ushort4 c = ((const ushort4*)(parts + 2 * P))[i];
  o.x += r.x + bf2f(a.x) + bf2f(b.x) + bf2f(c.x);
  o.y += r.y + bf2f(a.y) + bf2f(b.y) + bf2f(c.y);
  o.z += r.z + bf2f(a.z) + bf2f(b.z) + bf2f(c.z);
  o.w += r.w + bf2f(a.w) + bf2f(b.w) + bf2f(c.w);
  ((float4*)out)[i] = o;
}

extern "C" void kernel_launch(void* const* d_in, const int* in_sizes, int n_in,
                              void* d_out, int out_size, void* d_ws,
                              size_t ws_size, hipStream_t stream) {
  const float* x     = (const float*)d_in[0];
  const float* an_w  = (const float*)d_in[1];
  const float* an_b  = (const float*)d_in[2];
  const float* q_w   = (const float*)d_in[3];
  const float* q_b   = (const float*)d_in[4];
  const float* k_w   = (const float*)d_in[5];
  const float* k_b   = (const float*)d_in[6];
  const float* v_w   = (const float*)d_in[7];
  const float* v_b   = (const float*)d_in[8];
  const float* o_w   = (const float*)d_in[9];
  const float* o_b   = (const float*)d_in[10];
  const float* fn_w  = (const float*)d_in[11];
  const float* fn_b  = (const float*)d_in[12];
  const float* ff1_w = (const float*)d_in[13];
  const float* ff1_b = (const float*)d_in[14];
  const float* ff2_w = (const float*)d_in[15];
  const float* ff2_b = (const float*)d_in[16];

  char* ws = (char*)d_ws;
  const size_t MB = 1ull << 20;
  unsigned short* xn    = (unsigned short*)(ws + 0);       // 8MB; x2n later
  float2*         mlb   = (float2*)(ws + 0);               // 1MB during attn (xn dead)
  unsigned short* qkvwb = (unsigned short*)(ws + 8 * MB);  // 6MB [3072][1024]
  unsigned short* owb   = (unsigned short*)(ws + 14 * MB); // 2MB
  unsigned short* f1wb  = (unsigned short*)(ws + 16 * MB); // 8MB
  unsigned short* f2wb  = (unsigned short*)(ws + 24 * MB); // 8MB
  unsigned short* QKm   = (unsigned short*)(ws + 32 * MB); // 16MB [SQ][2048]
  unsigned short* Vtm   = (unsigned short*)(ws + 48 * MB); // 8MB [1024][SQ]
  unsigned short* ctx   = (unsigned short*)(ws + 56 * MB); // 8MB
  float*          bAll  = (float*)(ws + 56 * MB);          // 12KB (dead pre-ctx)
  float*          x2    = (float*)(ws + 64 * MB);          // 16MB fp32
  unsigned short* ctxP  = (unsigned short*)(ws + 64 * MB); // 16MB during attn (x2 later)
  unsigned short* hbuf  = (unsigned short*)(ws + 32 * MB); // 32MB reuse QK/Vt/ctx
  unsigned short* x2n   = xn;
  unsigned short* parts = (unsigned short*)(ws + 0);       // 24MB during FF2 (all dead)

  cvt6_kernel<<<12288, 256, 0, stream>>>(q_w, k_w, v_w, o_w, ff1_w, ff2_w, qkvwb);
  bias3_kernel<<<3, 256, 0, stream>>>(q_b, k_b, v_b, bAll);

  ln_kernel<<<SQ, 256, 0, stream>>>(x, an_w, an_b, xn);

  // fused QKV projection (256^2): QKm (Q,K) + Vtm (V transposed)
  gemm256<4><<<dim3(SQ / 256, 3072 / 256), 512, 0, stream>>>(
      xn, qkvwb, bAll, QKm, Vtm, SQ, 3072, HID);

  // attention, KV-split x2 -> partials, then combine
  attn_kernel<<<dim3(32, 32), 256, 0, stream>>>(QKm, Vtm, ctxP, mlb);
  combine2_kernel<<<(SQ * HID / 8) / 256, 256, 0, stream>>>(ctxP, mlb, ctx);

  // O projection + residual -> x2 (fp32)
  gemm128_res<<<dim3(SQ / 128, HID / 128), 256, 0, stream>>>(
      ctx, owb, o_b, x, x2, SQ, HID, HID);

  ln_kernel<<<SQ, 256, 0, stream>>>(x2, fn_w, fn_b, x2n);

  // FF1 + relu -> hbuf (256^2)
  gemm256<1><<<dim3(SQ / 256, INTER_DIM / 256), 512, 0, stream>>>(
      x2n, f1wb, ff1_b, hbuf, nullptr, SQ, INTER_DIM, HID);

  // FF2 split-K/4 (256^2): z==3 -> d_out f32 (acc+bias); z<3 -> bf16 parts
  gemm256<6><<<dim3(SQ / 256, HID / 256, 4), 512, 0, stream>>>(
      hbuf, f2wb, ff2_b, (float*)d_out, parts, SQ, HID, INTER_DIM);

  // d_out += p0+p1+p2 + x2
  combine4_kernel<<<(SQ * HID / 4) / 256, 256, 0, stream>>>(
      (float*)d_out, parts, x2);
}

// Round 7
// 425.309 us; speedup vs baseline: 1.0809x; 1.0809x over previous
//
#include <hip/hip_runtime.h>
#include <hip/hip_bf16.h>

#define SQ 4096
#define HID 1024
#define INTER_DIM 4096
#define NH 16
#define DH 64
#define SCALE_Q 0.18033688f  // 0.125 * log2(e), folded into q_w/q_b

typedef __attribute__((ext_vector_type(4))) float f32x4;
typedef __attribute__((ext_vector_type(16))) float f32x16;
typedef __attribute__((ext_vector_type(8))) short bf16x8;

__device__ __forceinline__ float bf2f(unsigned short u) {
  union { float f; unsigned int i; } v; v.i = ((unsigned int)u) << 16; return v.f;
}
__device__ __forceinline__ unsigned short f2bf(float f) {
  union { float f; unsigned int i; } v; v.f = f;
  unsigned int i = v.i;
  return (unsigned short)((i + 0x7FFFu + ((i >> 16) & 1u)) >> 16);
}

__device__ __forceinline__ void load_lds16(const void* g, void* l) {
  __builtin_amdgcn_global_load_lds(
      (const __attribute__((address_space(1))) void*)g,
      (__attribute__((address_space(3))) void*)l, 16, 0, 0);
}

__device__ __forceinline__ int cvtpk_bf16(float a, float b) {
  int r;
  asm("v_cvt_pk_bf16_f32 %0, %1, %2" : "=v"(r) : "v"(a), "v"(b));
  return r;
}

// native 2^x (log2-domain softmax). s_nop covers trans->VALU hazard.
__device__ __forceinline__ float fexp2(float x) {
  float r;
  asm("v_exp_f32 %0, %1\n\ts_nop 1" : "=v"(r) : "v"(x));
  return r;
}

// ---------------- fused weight conversion fp32 -> bf16 ----------------
__global__ __launch_bounds__(256) void cvt6_kernel(
    const float* __restrict__ s0, const float* __restrict__ s1,
    const float* __restrict__ s2, const float* __restrict__ s3,
    const float* __restrict__ s4, const float* __restrict__ s5,
    unsigned short* __restrict__ dst) {
  const int b = blockIdx.x;
  const float* src;
  int lb;
  size_t base4;
  if (b < 4096) {
    const int r = b >> 10;
    lb = b & 1023;
    src = (r == 0) ? s0 : (r == 1) ? s1 : (r == 2) ? s2 : s3;
    base4 = (size_t)r << 18;
  } else if (b < 8192) {
    lb = b - 4096; src = s4; base4 = 1u << 20;
  } else {
    lb = b - 8192; src = s5; base4 = 2u << 20;
  }
  const float sc = (b < 1024) ? SCALE_Q : 1.0f;
  const int i = lb * 256 + threadIdx.x;
  const float4 v4 = ((const float4*)src)[i];
  ushort4 o4;
  o4.x = f2bf(v4.x * sc); o4.y = f2bf(v4.y * sc);
  o4.z = f2bf(v4.z * sc); o4.w = f2bf(v4.w * sc);
  ((ushort4*)dst)[base4 + i] = o4;
}

// ---------------- concat q/k/v biases (q scaled) ----------------
__global__ __launch_bounds__(256) void bias3_kernel(
    const float* __restrict__ qb, const float* __restrict__ kb,
    const float* __restrict__ vb, float* __restrict__ dst) {
  const int b = blockIdx.x, t = threadIdx.x;
  const float* s = (b == 0) ? qb : (b == 1) ? kb : vb;
  float4 v = ((const float4*)s)[t];
  if (b == 0) { v.x *= SCALE_Q; v.y *= SCALE_Q; v.z *= SCALE_Q; v.w *= SCALE_Q; }
  ((float4*)dst)[b * 256 + t] = v;
}

// ---------------- mean-only layernorm -> bf16 ----------------
__global__ __launch_bounds__(256) void ln_kernel(
    const float* __restrict__ x, const float* __restrict__ w,
    const float* __restrict__ b, unsigned short* __restrict__ out) {
  const int row = blockIdx.x;
  const int t = threadIdx.x;
  const float4 v = ((const float4*)(x + (size_t)row * HID))[t];
  float s = v.x + v.y + v.z + v.w;
  #pragma unroll
  for (int off = 32; off > 0; off >>= 1) s += __shfl_xor(s, off);
  __shared__ float red[4];
  if ((t & 63) == 0) red[t >> 6] = s;
  __syncthreads();
  const float mean = (red[0] + red[1] + red[2] + red[3]) * (1.0f / HID);
  const float4 wv = ((const float4*)w)[t];
  const float4 bv = ((const float4*)b)[t];
  ushort4 o;
  o.x = f2bf(wv.x * (v.x - mean) + bv.x);
  o.y = f2bf(wv.y * (v.y - mean) + bv.y);
  o.z = f2bf(wv.z * (v.z - mean) + bv.z);
  o.w = f2bf(wv.w * (v.w - mean) + bv.w);
  ((ushort4*)(out + (size_t)row * HID))[t] = o;
}

// ---------------- FF2 combine: out += p1 + res ----------------
__global__ __launch_bounds__(256) void combine_kernel(
    float* __restrict__ out, const float* __restrict__ p1,
    const float* __restrict__ res) {
  const int i = blockIdx.x * 256 + threadIdx.x;
  float4 o = ((const float4*)out)[i];
  const float4 a = ((const float4*)p1)[i];
  const float4 r = ((const float4*)res)[i];
  o.x += a.x + r.x; o.y += a.y + r.y; o.z += a.z + r.z; o.w += a.w + r.w;
  ((float4*)out)[i] = o;
}

// ---------------- O combine: x2 += bf16(p1) + res ----------------
__global__ __launch_bounds__(256) void combineO_kernel(
    float* __restrict__ x2, const unsigned short* __restrict__ p1,
    const float* __restrict__ res) {
  const int i = blockIdx.x * 256 + threadIdx.x;
  float4 o = ((const float4*)x2)[i];
  const ushort4 a = ((const ushort4*)p1)[i];
  const float4 r = ((const float4*)res)[i];
  o.x += bf2f(a.x) + r.x; o.y += bf2f(a.y) + r.y;
  o.z += bf2f(a.z) + r.z; o.w += bf2f(a.w) + r.w;
  ((float4*)x2)[i] = o;
}

// ---------------- GEMM: C[M][N] = A[M][K] * B[N][K]^T + bias ----
// Double-buffered LDS, prefetch-before-compute (2-phase).
// MODE 1: bf16 out = relu(acc+bias)
// MODE 4: fused QKV: col<2048 -> bf16 C0[row*2048+col];
//         col>=2048 -> bf16 transposed C1[(col-2048)*M + row]
// MODE 5: split-K/2 via z: z=0 -> f32 C0 = acc+bias; z=1 -> f32 C1 = acc
// MODE 7: split-K/2 via z: z=0 -> f32 C0 = acc+bias; z=1 -> bf16 C1 = acc
template <int MODE>
__global__ __launch_bounds__(256) void gemm_bt(
    const unsigned short* __restrict__ A, const unsigned short* __restrict__ B,
    const float* __restrict__ bias, void* __restrict__ Cout,
    void* __restrict__ Cout2, int M, int N, int K) {
  __shared__ __align__(16) unsigned short As[2][128 * 32];
  __shared__ __align__(16) unsigned short Bs[2][128 * 32];
  const int t = threadIdx.x;
  const int lane = t & 63;
  const int wave = t >> 6;
  const int g = lane >> 4;
  const int lr = lane & 15;
  const int waveM = wave >> 1, waveN = wave & 1;
  const int rowBase = blockIdx.x * 128;
  const int colBase = blockIdx.y * 128;
  const int Keff = (MODE == 5 || MODE == 7) ? (K >> 1) : K;
  const int kBase = (MODE == 5 || MODE == 7) ? blockIdx.z * Keff : 0;

  f32x4 acc[4][4];
  #pragma unroll
  for (int m = 0; m < 4; ++m)
    #pragma unroll
    for (int n = 0; n < 4; ++n) acc[m][n] = (f32x4){0.f, 0.f, 0.f, 0.f};

  const int c0 = t, c1 = t + 256;
  const int r0s = c0 >> 2, s0 = (c0 & 3) ^ (r0s & 3);
  const int r1s = c1 >> 2, s1 = (c1 & 3) ^ (r1s & 3);
  const unsigned short* gA0 = A + (size_t)(rowBase + r0s) * K + kBase + s0 * 8;
  const unsigned short* gA1 = A + (size_t)(rowBase + r1s) * K + kBase + s1 * 8;
  const unsigned short* gB0 = B + (size_t)(colBase + r0s) * K + kBase + s0 * 8;
  const unsigned short* gB1 = B + (size_t)(colBase + r1s) * K + kBase + s1 * 8;

  load_lds16(gA0, &As[0][wave * 512]);
  load_lds16(gA1, &As[0][2048 + wave * 512]);
  load_lds16(gB0, &Bs[0][wave * 512]);
  load_lds16(gB1, &Bs[0][2048 + wave * 512]);
  __syncthreads();

  const int nk = Keff >> 5;
  for (int kt = 0; kt < nk; ++kt) {
    const int buf = kt & 1;
    if (kt + 1 < nk) {
      const int k0 = (kt + 1) << 5;
      load_lds16(gA0 + k0, &As[buf ^ 1][wave * 512]);
      load_lds16(gA1 + k0, &As[buf ^ 1][2048 + wave * 512]);
      load_lds16(gB0 + k0, &Bs[buf ^ 1][wave * 512]);
      load_lds16(gB1 + k0, &Bs[buf ^ 1][2048 + wave * 512]);
    }
    bf16x8 af[4], bfr[4];
    #pragma unroll
    for (int m = 0; m < 4; ++m) {
      const int r = waveM * 64 + m * 16 + lr;
      af[m] = *(const bf16x8*)&As[buf][r * 32 + ((g ^ (r & 3)) << 3)];
    }
    #pragma unroll
    for (int n = 0; n < 4; ++n) {
      const int c = waveN * 64 + n * 16 + lr;
      bfr[n] = *(const bf16x8*)&Bs[buf][c * 32 + ((g ^ (c & 3)) << 3)];
    }
    #pragma unroll
    for (int m = 0; m < 4; ++m)
      #pragma unroll
      for (int n = 0; n < 4; ++n)
        acc[m][n] = __builtin_amdgcn_mfma_f32_16x16x32_bf16(af[m], bfr[n],
                                                            acc[m][n], 0, 0, 0);
    __syncthreads();
  }

  const int crow0 = rowBase + waveM * 64;
  const int ccol0 = colBase + waveN * 64;
  #pragma unroll
  for (int n = 0; n < 4; ++n) {
    const int col = ccol0 + n * 16 + lr;
    const float bv = bias[col];
    #pragma unroll
    for (int m = 0; m < 4; ++m) {
      const int row0 = crow0 + m * 16 + g * 4;
      if (MODE == 4) {
        if (col < 2048) {
          #pragma unroll
          for (int j = 0; j < 4; ++j)
            ((unsigned short*)Cout)[(size_t)(row0 + j) * 2048 + col] =
                f2bf(acc[m][n][j] + bv);
        } else {
          ushort4 o4;
          o4.x = f2bf(acc[m][n][0] + bv);
          o4.y = f2bf(acc[m][n][1] + bv);
          o4.z = f2bf(acc[m][n][2] + bv);
          o4.w = f2bf(acc[m][n][3] + bv);
          *(ushort4*)&((unsigned short*)Cout2)[(size_t)(col - 2048) * M + row0] = o4;
        }
      } else if (MODE == 1) {
        #pragma unroll
        for (int j = 0; j < 4; ++j)
          ((unsigned short*)Cout)[(size_t)(row0 + j) * N + col] =
              f2bf(fmaxf(acc[m][n][j] + bv, 0.f));
      } else if (MODE == 5) {
        if (blockIdx.z == 0) {
          #pragma unroll
          for (int j = 0; j < 4; ++j)
            ((float*)Cout)[(size_t)(row0 + j) * N + col] = acc[m][n][j] + bv;
        } else {
          #pragma unroll
          for (int j = 0; j < 4; ++j)
            ((float*)Cout2)[(size_t)(row0 + j) * N + col] = acc[m][n][j];
        }
      } else {  // MODE 7
        if (blockIdx.z == 0) {
          #pragma unroll
          for (int j = 0; j < 4; ++j)
            ((float*)Cout)[(size_t)(row0 + j) * N + col] = acc[m][n][j] + bv;
        } else {
          #pragma unroll
          for (int j = 0; j < 4; ++j)
            ((unsigned short*)Cout2)[(size_t)(row0 + j) * N + col] =
                f2bf(acc[m][n][j]);
        }
      }
    }
  }
}

// ---------------- flash attention, swapped-QK, 2-wave blocks ----------------
// grid: 1024 blocks (xcd-swizzled: 2 heads/XCD), 128 threads = 2 waves,
// each wave owns 32 q-rows (64 q-rows/block). KVBLK=64, dbuf K/V LDS.
// 4 blocks/CU (vs 2 before) — occupancy from grid, no extra HBM traffic.
__global__ __launch_bounds__(128, 2) void attn_kernel(
    const unsigned short* __restrict__ QK,  // [SQ][2048]: Q 0-1023, K 1024-2047
    const unsigned short* __restrict__ Vt,  // [HID][SQ]
    unsigned short* __restrict__ ctx) {     // [SQ][HID]
  const int s = blockIdx.y * gridDim.x + blockIdx.x;  // 0..1023
  const int q6 = s >> 3;                              // 0..127
  const int h = (s & 7) * 2 + (q6 >> 6);
  const int qt = q6 & 63;

  const int t = threadIdx.x;   // 0..127
  const int lane = t & 63;
  const int w = t >> 6;        // 0..1
  const int ql = lane & 31;
  const int hi = lane >> 5;

  __shared__ __align__(16) unsigned short Ks[2][64 * 64];
  __shared__ __align__(16) unsigned short Vs[2][64 * 64];

  const int qbase = qt * 64 + w * 32;
  const unsigned short* qptr =
      QK + (size_t)(qbase + ql) * 2048 + h * DH + hi * 8;
  bf16x8 qf[4];
  #pragma unroll
  for (int ks = 0; ks < 4; ++ks) qf[ks] = *(const bf16x8*)(qptr + ks * 16);

  // staging: 128 threads x 4 chunks per matrix per tile.
  // chunk i covers rows i*16 + (t>>3); slot swizzle invariant mod 8.
  const int cr = t >> 3, cs = t & 7;
  const int sw = (cs ^ (cr & 7)) << 3;
  const unsigned short* gK0 = QK + (size_t)cr * 2048 + 1024 + h * DH + sw;
  const unsigned short* gV0 = Vt + (size_t)(h * DH + cr) * SQ + sw;

  float mreg = 0.f, lreg = 0.f;
  f32x16 oacc0 = 0.f, oacc1 = 0.f;

  #pragma unroll
  for (int i = 0; i < 4; ++i) {
    load_lds16(gK0 + (size_t)i * 16 * 2048, &Ks[0][i * 1024 + w * 512]);
    load_lds16(gV0 + (size_t)i * 16 * SQ, &Vs[0][i * 1024 + w * 512]);
  }

  for (int kt = 0; kt < SQ / 64; ++kt) {
    const int buf = kt & 1;
    __syncthreads();  // staged buf ready (vmcnt drain), prev compute done
    if (kt + 1 < SQ / 64) {
      const size_t ko = (size_t)(kt + 1) * 64 * 2048;
      const int vo = (kt + 1) * 64;
      #pragma unroll
      for (int i = 0; i < 4; ++i) {
        load_lds16(gK0 + ko + (size_t)i * 16 * 2048,
                   &Ks[buf ^ 1][i * 1024 + w * 512]);
        load_lds16(gV0 + vo + (size_t)i * 16 * SQ,
                   &Vs[buf ^ 1][i * 1024 + w * 512]);
      }
    }
    const unsigned short* KsB = &Ks[buf][0];
    const unsigned short* VsB = &Vs[buf][0];

    // swapped QK^T with shifted C-init: st = S - mreg directly
    f32x16 st0, st1;
    #pragma unroll
    for (int r = 0; r < 16; ++r) { st0[r] = -mreg; st1[r] = -mreg; }
    __builtin_amdgcn_s_setprio(1);
    #pragma unroll
    for (int ks = 0; ks < 4; ++ks) {
      const int sl = ((((ks << 1) | hi) ^ (ql & 7)) << 3);
      const bf16x8 k0 = *(const bf16x8*)&KsB[ql * 64 + sl];
      const bf16x8 k1 = *(const bf16x8*)&KsB[(32 + ql) * 64 + sl];
      st0 = __builtin_amdgcn_mfma_f32_32x32x16_bf16(k0, qf[ks], st0, 0, 0, 0);
      st1 = __builtin_amdgcn_mfma_f32_32x32x16_bf16(k1, qf[ks], st1, 0, 0, 0);
    }
    __builtin_amdgcn_s_setprio(0);

    bf16x8 vf0[4], vf1[4];
    #pragma unroll
    for (int ks = 0; ks < 4; ++ks) {
      const int sl = ((((ks << 1) | hi) ^ (ql & 7)) << 3);
      vf0[ks] = *(const bf16x8*)&VsB[ql * 64 + sl];
      vf1[ks] = *(const bf16x8*)&VsB[(32 + ql) * 64 + sl];
    }

    // ---- online softmax (log2 domain, values pre-shifted by -mreg) ----
    float tr[16];
    #pragma unroll
    for (int r = 0; r < 16; ++r) tr[r] = fmaxf(st0[r], st1[r]);
    #pragma unroll
    for (int s2 = 8; s2 > 0; s2 >>= 1)
      #pragma unroll
      for (int r = 0; r < s2; ++r) tr[r] = fmaxf(tr[r], tr[r + s2]);
    const float mx = fmaxf(tr[0], __shfl_xor(tr[0], 32));

    if (!__all(mx <= 8.0f)) {  // defer-max rescale
      const float mpos = fmaxf(mx, 0.f);
      const float corr = fexp2(-mpos);
      mreg += mpos;
      lreg *= corr;
      #pragma unroll
      for (int r = 0; r < 16; ++r) { st0[r] -= mpos; st1[r] -= mpos; }
      #pragma unroll
      for (int r = 0; r < 16; ++r) {
        const float c = __shfl(corr, (r & 3) + 8 * (r >> 2) + 4 * hi);
        oacc0[r] *= c;
        oacc1[r] *= c;
      }
    }

    #pragma unroll
    for (int r = 0; r < 16; ++r) st0[r] = fexp2(st0[r]);
    #pragma unroll
    for (int r = 0; r < 16; ++r) st1[r] = fexp2(st1[r]);
    float ts[16];
    #pragma unroll
    for (int r = 0; r < 16; ++r) ts[r] = st0[r] + st1[r];
    #pragma unroll
    for (int s2 = 8; s2 > 0; s2 >>= 1)
      #pragma unroll
      for (int r = 0; r < s2; ++r) ts[r] += ts[r + s2];
    lreg += ts[0] + __shfl_xor(ts[0], 32);

    // ---- P -> A-frag via cvt_pk + permlane32_swap ----
    union { int wd[4]; bf16x8 v; } pa[4];
    #pragma unroll
    for (int half = 0; half < 2; ++half) {
      #pragma unroll
      for (int kk = 0; kk < 2; ++kk) {
        const int base = kk * 8;
        float p0, p1, p2, p3, p4, p5, p6, p7;
        if (half == 0) {
          p0 = st0[base + 0]; p1 = st0[base + 1]; p2 = st0[base + 2]; p3 = st0[base + 3];
          p4 = st0[base + 4]; p5 = st0[base + 5]; p6 = st0[base + 6]; p7 = st0[base + 7];
        } else {
          p0 = st1[base + 0]; p1 = st1[base + 1]; p2 = st1[base + 2]; p3 = st1[base + 3];
          p4 = st1[base + 4]; p5 = st1[base + 5]; p6 = st1[base + 6]; p7 = st1[base + 7];
        }
        const int d0 = cvtpk_bf16(p0, p1), sw0 = cvtpk_bf16(p4, p5);
        const int d1 = cvtpk_bf16(p2, p3), sw1 = cvtpk_bf16(p6, p7);
        auto a = __builtin_amdgcn_permlane32_swap(d0, sw0, false, false);
        auto b = __builtin_amdgcn_permlane32_swap(d1, sw1, false, false);
        const int ks = half * 2 + kk;
        pa[ks].wd[0] = a[0]; pa[ks].wd[1] = b[0];
        pa[ks].wd[2] = a[1]; pa[ks].wd[3] = b[1];
      }
    }

    // ---- PV ----
    __builtin_amdgcn_s_setprio(1);
    #pragma unroll
    for (int ks = 0; ks < 4; ++ks) {
      oacc0 = __builtin_amdgcn_mfma_f32_32x32x16_bf16(pa[ks].v, vf0[ks], oacc0, 0, 0, 0);
      oacc1 = __builtin_amdgcn_mfma_f32_32x32x16_bf16(pa[ks].v, vf1[ks], oacc1, 0, 0, 0);
    }
    __builtin_amdgcn_s_setprio(0);
  }

  // ---- epilogue: divide by l, write ctx ----
  const float linv = 1.0f / lreg;
  #pragma unroll
  for (int r = 0; r < 16; ++r) {
    const int qq = (r & 3) + 8 * (r >> 2) + 4 * hi;
    const float li = __shfl(linv, qq);
    unsigned short* cp = ctx + (size_t)(qbase + qq) * HID + h * DH + ql;
    cp[0] = f2bf(oacc0[r] * li);
    cp[32] = f2bf(oacc1[r] * li);
  }
}

extern "C" void kernel_launch(void* const* d_in, const int* in_sizes, int n_in,
                              void* d_out, int out_size, void* d_ws,
                              size_t ws_size, hipStream_t stream) {
  const float* x     = (const float*)d_in[0];
  const float* an_w  = (const float*)d_in[1];
  const float* an_b  = (const float*)d_in[2];
  const float* q_w   = (const float*)d_in[3];
  const float* q_b   = (const float*)d_in[4];
  const float* k_w   = (const float*)d_in[5];
  const float* k_b   = (const float*)d_in[6];
  const float* v_w   = (const float*)d_in[7];
  const float* v_b   = (const float*)d_in[8];
  const float* o_w   = (const float*)d_in[9];
  const float* o_b   = (const float*)d_in[10];
  const float* fn_w  = (const float*)d_in[11];
  const float* fn_b  = (const float*)d_in[12];
  const float* ff1_w = (const float*)d_in[13];
  const float* ff1_b = (const float*)d_in[14];
  const float* ff2_w = (const float*)d_in[15];
  const float* ff2_b = (const float*)d_in[16];

  char* ws = (char*)d_ws;
  const size_t MB = 1ull << 20;
  unsigned short* xn    = (unsigned short*)(ws + 0);       // 8MB; x2n later
  unsigned short* p1o   = (unsigned short*)(ws + 0);       // 8MB during O (xn dead)
  unsigned short* qkvwb = (unsigned short*)(ws + 8 * MB);  // 6MB [3072][1024]
  unsigned short* owb   = (unsigned short*)(ws + 14 * MB); // 2MB
  unsigned short* f1wb  = (unsigned short*)(ws + 16 * MB); // 8MB
  unsigned short* f2wb  = (unsigned short*)(ws + 24 * MB); // 8MB
  unsigned short* QKm   = (unsigned short*)(ws + 32 * MB); // 16MB [SQ][2048]
  unsigned short* Vtm   = (unsigned short*)(ws + 48 * MB); // 8MB [1024][SQ]
  unsigned short* ctx   = (unsigned short*)(ws + 56 * MB); // 8MB
  float*          bAll  = (float*)(ws + 56 * MB);          // 12KB (dead pre-ctx)
  float*          x2    = (float*)(ws + 64 * MB);          // 16MB fp32
  unsigned short* hbuf  = (unsigned short*)(ws + 32 * MB); // 32MB reuse QK/Vt/ctx
  unsigned short* x2n   = xn;
  float*          p1    = (float*)(ws + 0);                // 16MB during FF2 (all dead)

  cvt6_kernel<<<12288, 256, 0, stream>>>(q_w, k_w, v_w, o_w, ff1_w, ff2_w, qkvwb);
  bias3_kernel<<<3, 256, 0, stream>>>(q_b, k_b, v_b, bAll);

  ln_kernel<<<SQ, 256, 0, stream>>>(x, an_w, an_b, xn);

  // fused QKV projection: QKm (Q,K) + Vtm (V transposed)
  gemm_bt<4><<<dim3(SQ / 128, 3072 / 128), 256, 0, stream>>>(
      xn, qkvwb, bAll, QKm, Vtm, SQ, 3072, HID);

  // attention: 1024 blocks x 128 threads
  attn_kernel<<<dim3(32, 32), 128, 0, stream>>>(QKm, Vtm, ctx);

  // O projection split-K/2: z=0 -> x2 f32 (acc+bias); z=1 -> p1o bf16 (acc)
  gemm_bt<7><<<dim3(SQ / 128, HID / 128, 2), 256, 0, stream>>>(
      ctx, owb, o_b, x2, p1o, SQ, HID, HID);
  // x2 += bf16(p1o) + x (residual)
  combineO_kernel<<<(SQ * HID / 4) / 256, 256, 0, stream>>>(x2, p1o, x);

  ln_kernel<<<SQ, 256, 0, stream>>>(x2, fn_w, fn_b, x2n);

  // FF1 + relu -> hbuf
  gemm_bt<1><<<dim3(SQ / 128, INTER_DIM / 128), 256, 0, stream>>>(
      x2n, f1wb, ff1_b, hbuf, nullptr, SQ, INTER_DIM, HID);

  // FF2 split-K/2: z=0 -> d_out f32 (acc+bias); z=1 -> p1 f32 (acc)
  gemm_bt<5><<<dim3(SQ / 128, HID / 128, 2), 256, 0, stream>>>(
      hbuf, f2wb, ff2_b, (float*)d_out, p1, SQ, HID, INTER_DIM);

  // d_out += p1 + x2 (residual)
  combine_kernel<<<(SQ * HID / 4) / 256, 256, 0, stream>>>(
      (float*)d_out, p1, x2);
}